// Round 11
// baseline (1367.236 us; speedup 1.0000x reference)
//
#include <hip/hip_runtime.h>
#include <stdint.h>

typedef unsigned short u16;
typedef __bf16 bf16x8 __attribute__((ext_vector_type(8)));
typedef float f32x4 __attribute__((ext_vector_type(4)));

#define N_TOK 16384
#define DIM   1024
#define NEXP  8
#define HID   4096
#define MTILES 264          // >= max sum of per-expert ceil(count/128) tiles
#define PADROWS 33792       // MTILES*128

__device__ __forceinline__ u16 f2bf(float f) {
  uint32_t u = __builtin_bit_cast(uint32_t, f);
  u += 0x7fffu + ((u >> 16) & 1u);   // RNE for finite values
  return (u16)(u >> 16);
}

__device__ __forceinline__ float bf2f(u16 v) {
  uint32_t u = (uint32_t)v << 16;
  return __builtin_bit_cast(float, u);
}

__device__ __forceinline__ void gload16(const void* g, void* l) {
  __builtin_amdgcn_global_load_lds(
      (const __attribute__((address_space(1))) uint32_t*)g,
      (__attribute__((address_space(3))) uint32_t*)l, 16, 0, 0);
}

// ---------------- init / transpose ----------------

__global__ void k_zero(int* counts) {
  if (threadIdx.x < NEXP) counts[threadIdx.x] = 0;
}

// src: [E][R][C] f32  ->  dst: [E][C][R] bf16
__global__ void k_tcast(const float* __restrict__ src, u16* __restrict__ dst,
                        int R, int C) {
  __shared__ float tile[32][33];
  int nc = C >> 5, nr = R >> 5;
  int t = blockIdx.x;
  int cb = t % nc; t /= nc;
  int rb = t % nr; int ee = t / nr;
  const float* s0 = src + ((size_t)ee * R + (size_t)rb * 32) * C + cb * 32;
  int tx = threadIdx.x & 31, ty = threadIdx.x >> 5;
#pragma unroll
  for (int i = 0; i < 4; ++i)
    tile[ty + i * 8][tx] = s0[(size_t)(ty + i * 8) * C + tx];
  __syncthreads();
  u16* d0 = dst + ((size_t)ee * C + (size_t)cb * 32) * R + rb * 32;
#pragma unroll
  for (int i = 0; i < 4; ++i)
    d0[(size_t)(ty + i * 8) * R + tx] = f2bf(tile[tx][ty + i * 8]);
}

// ---------------- gate (+ fused x -> bf16 cast); NO global atomics ----------

__global__ __launch_bounds__(256) void k_gate(
    const float* __restrict__ x, const float* __restrict__ Wg,
    const float* __restrict__ bg, u16* __restrict__ xb,
    int* __restrict__ tok_e, float* __restrict__ tok_g,
    float* __restrict__ blocksums) {
  __shared__ float wg_s[NEXP * DIM];   // transposed: [e][k]
  __shared__ float s4[4];
  for (int i = threadIdx.x; i < NEXP * DIM; i += 256) {
    int k = i >> 3, e = i & 7;
    wg_s[e * DIM + k] = Wg[i];
  }
  __syncthreads();
  int lane = threadIdx.x & 63, wv = threadIdx.x >> 6;
  int n = blockIdx.x * 4 + wv;
  const float4* xr4 = (const float4*)(x + (size_t)n * DIM);
  float4 xv[4];
#pragma unroll
  for (int i = 0; i < 4; ++i) xv[i] = xr4[lane + 64 * i];
  ushort4* xo4 = (ushort4*)(xb + (size_t)n * DIM);
#pragma unroll
  for (int i = 0; i < 4; ++i) {
    ushort4 p;
    p.x = f2bf(xv[i].x); p.y = f2bf(xv[i].y);
    p.z = f2bf(xv[i].z); p.w = f2bf(xv[i].w);
    xo4[lane + 64 * i] = p;
  }
  float acc[8];
#pragma unroll
  for (int e = 0; e < 8; ++e) {
    const float4* w4 = (const float4*)(wg_s + e * DIM);
    float a = 0.f;
#pragma unroll
    for (int i = 0; i < 4; ++i) {
      float4 wv4 = w4[lane + 64 * i];
      a += xv[i].x * wv4.x + xv[i].y * wv4.y + xv[i].z * wv4.z +
           xv[i].w * wv4.w;
    }
    acc[e] = a;
  }
#pragma unroll
  for (int e = 0; e < 8; ++e)
#pragma unroll
    for (int off = 32; off > 0; off >>= 1)
      acc[e] += __shfl_xor(acc[e], off);

  if (lane == 0) {
    float l0 = -1e30f, l1 = -1e30f; int e0 = 0, e1 = 0;
#pragma unroll
    for (int e = 0; e < 8; ++e) {
      float v = acc[e] + bg[e];
      if (v > l0) { l1 = l0; e1 = e0; l0 = v; e0 = e; }
      else if (v > l1) { l1 = v; e1 = e; }
    }
    // renormalized top-2 softmax gates depend only on the top-2 logits
    float g0 = 1.f / (1.f + expf(l1 - l0));
    float g1 = 1.f - g0;
    tok_e[2 * n] = e0; tok_e[2 * n + 1] = e1;
    tok_g[2 * n] = g0; tok_g[2 * n + 1] = g1;
    s4[wv] = g0;
  }
  __syncthreads();
  if (threadIdx.x == 0) blocksums[blockIdx.x] = s4[0] + s4[1] + s4[2] + s4[3];
}

// ---------------- histogram of tok_e: 16 blocks, 128 global atomics total ----

__global__ __launch_bounds__(256) void k_hist(const int* __restrict__ tok_e,
                                              int* __restrict__ counts) {
  __shared__ int lcnt[8];
  if (threadIdx.x < 8) lcnt[threadIdx.x] = 0;
  __syncthreads();
  int base4 = (blockIdx.x * 256 + threadIdx.x) * 2;   // 2x int4 = 8 entries
  const int4* t4 = (const int4*)tok_e;
  int4 a = t4[base4], b = t4[base4 + 1];
  int v[8] = {a.x, a.y, a.z, a.w, b.x, b.y, b.z, b.w};
  int c[8];
#pragma unroll
  for (int ee = 0; ee < 8; ++ee) {
    int s = 0;
#pragma unroll
    for (int i = 0; i < 8; ++i) s += (v[i] == ee);
    c[ee] = s;
  }
  int lane = threadIdx.x & 63;
#pragma unroll
  for (int ee = 0; ee < 8; ++ee) {
    int s = c[ee];
#pragma unroll
    for (int off = 32; off > 0; off >>= 1) s += __shfl_xor(s, off);
    if (lane == 0 && s) atomicAdd(&lcnt[ee], s);
  }
  __syncthreads();
  if (threadIdx.x < 8 && lcnt[threadIdx.x])
    atomicAdd(&counts[threadIdx.x], lcnt[threadIdx.x]);
}

// ---------------- routing setup (1 block) ----------------

__global__ __launch_bounds__(256) void k_setup(
    const int* __restrict__ counts, const float* __restrict__ blocksums,
    int* __restrict__ padded_off, int* __restrict__ cursor,
    int* __restrict__ row2tok, float* __restrict__ aux_out) {
  __shared__ float red[256];
  __shared__ int off_s[9];
  float s = 0.f;
  for (int i = threadIdx.x; i < 4096; i += 256) s += blocksums[i];
  red[threadIdx.x] = s;
  __syncthreads();
  for (int st = 128; st > 0; st >>= 1) {
    if (threadIdx.x < st) red[threadIdx.x] += red[threadIdx.x + st];
    __syncthreads();
  }
  if (threadIdx.x == 0) {
    int off = 0, nact = 0;
    for (int e = 0; e < 8; ++e) {
      off_s[e] = off;
      int c = counts[e];
      if (c > 0) nact++;
      off += ((c + 127) >> 7) << 7;   // pad each expert to 128-row tiles
      cursor[e] = 0;
    }
    off_s[8] = off;
    for (int e = 0; e <= 8; ++e) padded_off[e] = off_s[e];
    float m = red[0] / (float)N_TOK;
    *aux_out = (float)nact * m * m;
  }
  __syncthreads();
  // padding slots reference token 0 (valid data); no slot points at them
  for (int idx = threadIdx.x; idx < NEXP * 128; idx += 256) {
    int e = idx >> 7, i = idx & 127;
    int slot = off_s[e] + counts[e] + i;
    if (slot < off_s[e + 1]) row2tok[slot] = 0;
  }
}

// ---------------- scatter: block-aggregated; stores slots back into tok_e ----

__global__ __launch_bounds__(256) void k_scatter(
    int* __restrict__ tok_e, const int* __restrict__ padded_off,
    int* __restrict__ cursor, int* __restrict__ row2tok) {
  __shared__ int lcnt[8], lbase[8];
  if (threadIdx.x < 8) lcnt[threadIdx.x] = 0;
  __syncthreads();
  int n = blockIdx.x * 256 + threadIdx.x;
  int e0 = tok_e[2 * n], e1 = tok_e[2 * n + 1];
  int p0 = atomicAdd(&lcnt[e0], 1);
  int p1 = atomicAdd(&lcnt[e1], 1);
  __syncthreads();
  if (threadIdx.x < 8 && lcnt[threadIdx.x])
    lbase[threadIdx.x] = atomicAdd(&cursor[threadIdx.x], lcnt[threadIdx.x]);
  __syncthreads();
  int s0 = padded_off[e0] + lbase[e0] + p0;
  int s1 = padded_off[e1] + lbase[e1] + p1;
  row2tok[s0] = n;
  row2tok[s1] = n;
  tok_e[2 * n] = s0;           // tok_e now holds the slot indices
  tok_e[2 * n + 1] = s1;
}

// ---------------- grouped GEMM, 128x128 tile, BK=32 ----------------
// r9 counted-vmcnt pipeline, A-only LDS:
//  - A staged via global_load_lds into triple-buffered LDS (24 KB), 2-deep
//    prefetch, chunk-XOR swizzled (both-sides, rule #21).
//  - B fragments loaded DIRECTLY global->VGPR (the [N][K] transposed weight
//    layout makes each fragment a contiguous 16 B per lane), prefetched one
//    iter ahead into a second register set. B panels are L2-resident (shared
//    by all row-tile siblings at the same n0) -> removing the LDS hop halves
//    LDS traffic (48->24 KB per block-iter).
//  vmem queue per iter: 2 A-gloads + 4 B-loads = 6.
//    per iter: STG_A(k+2); LDB(k+1); vmcnt(6)  [retires A(k+1)+B(k)]
//              barrier; CMP(k) {ds_read A, mfma w/ B regs}; lgkmcnt(0); barrier
//  MODE 0: h = relu(gather(x) @ W1t[e] + b1)   -> bf16 rows stride HID
//  MODE 1: y = h @ W2t[e] + b2                 -> bf16 rows stride DIM

template <int KDIM, int MODE>
__global__ __launch_bounds__(256, 3) void k_gemm(
    const u16* __restrict__ Asrc, const u16* __restrict__ Wt,
    const float* __restrict__ bias, const int* __restrict__ row2tok,
    const int* __restrict__ padded_off, u16* __restrict__ Out) {
  __shared__ u16 Abuf[3][4096];   // [128 rows][32 k] bf16, linear dest
  constexpr int NDIM = MODE ? DIM : HID;
  int row0 = blockIdx.y * 128;
  if (row0 >= padded_off[8]) return;
  int e = 0;
  while (row0 >= padded_off[e + 1]) ++e;
  int n0 = blockIdx.x * 128;
  int tid = threadIdx.x, lane = tid & 63, wv = tid >> 6;
  int wm = wv >> 1, wn = wv & 1;
  int fr = lane & 15, fq = lane >> 4;
  int ra0 = tid >> 2, ra1 = 64 + (tid >> 2);
  // pre-swizzled A source chunk: physical chunk (tid&3) holds logical chunk
  // (tid&3)^((row>>1)&3); (row>>1)&3 == (tid>>3)&3 for both ra0 and ra1
  int ca = (((tid & 3) ^ ((tid >> 3) & 3))) * 8;
  const u16 *asrc0, *asrc1;
  if (MODE == 0) {
    asrc0 = Asrc + (size_t)row2tok[row0 + ra0] * KDIM + ca;
    asrc1 = Asrc + (size_t)row2tok[row0 + ra1] * KDIM + ca;
  } else {
    asrc0 = Asrc + (size_t)(row0 + ra0) * KDIM + ca;
    asrc1 = Asrc + (size_t)(row0 + ra1) * KDIM + ca;
  }
  // B fragment base: row (n0 + wn*64 + fr), k-chunk fq; fn stride = 16 rows
  const u16* bb = Wt + (size_t)e * (HID * DIM);
  const u16* bsrcf = bb + (size_t)(n0 + wn * 64 + fr) * KDIM + fq * 8;
  int lo = wv * 512;   // wave-uniform LDS elem offset (64 lanes * 8 u16)
  // swizzled A read: chunk fq of row (..+fr) is at physical fq^((fr>>1)&3)
  int sq = (fq ^ ((fr >> 1) & 3)) * 8;

  f32x4 acc[4][4];
#pragma unroll
  for (int i = 0; i < 4; ++i)
#pragma unroll
    for (int j = 0; j < 4; ++j) acc[i][j] = (f32x4){0.f, 0.f, 0.f, 0.f};
  bf16x8 av[4], bvp[4], bvn[4];

#define STG(b, kt)                                 \
  do {                                             \
    int ko = (kt) * 32;                            \
    gload16(asrc0 + ko, &Abuf[b][lo]);             \
    gload16(asrc1 + ko, &Abuf[b][2048 + lo]);      \
  } while (0)

#define LDB(dst, kt)                                                  \
  do {                                                                \
    size_t ko = (size_t)(kt) * 32;                                    \
    dst[0] = *(const bf16x8*)(bsrcf + ko);                            \
    dst[1] = *(const bf16x8*)(bsrcf + (size_t)16 * KDIM + ko);        \
    dst[2] = *(const bf16x8*)(bsrcf + (size_t)32 * KDIM + ko);        \
    dst[3] = *(const bf16x8*)(bsrcf + (size_t)48 * KDIM + ko);        \
  } while (0)

#define CMP(b)                                                                 \
  do {                                                                         \
    _Pragma("unroll") for (int fm = 0; fm < 4; ++fm)                           \
        av[fm] = *(const bf16x8*)&Abuf[b][(wm * 64 + fm * 16 + fr) * 32 + sq]; \
    _Pragma("unroll") for (int fm = 0; fm < 4; ++fm)                           \
        _Pragma("unroll") for (int fn = 0; fn < 4; ++fn)                       \
            acc[fm][fn] = __builtin_amdgcn_mfma_f32_16x16x32_bf16(             \
                av[fm], bvp[fn], acc[fm][fn], 0, 0, 0);                        \
  } while (0)

  constexpr int NK = KDIM / 32;
  STG(0, 0);
  STG(1, 1);
  LDB(bvp, 0);
  int rb = 0;
  for (int kt = 0; kt < NK - 2; ++kt) {
    int sb = rb + 2; if (sb >= 3) sb -= 3;
    STG(sb, kt + 2);
    LDB(bvn, kt + 1);
    asm volatile("s_waitcnt vmcnt(6)" ::: "memory");
    asm volatile("s_barrier" ::: "memory");
    CMP(rb);
    asm volatile("s_waitcnt lgkmcnt(0)" ::: "memory");
    asm volatile("s_barrier" ::: "memory");
    bvp[0] = bvn[0]; bvp[1] = bvn[1]; bvp[2] = bvn[2]; bvp[3] = bvn[3];
    if (++rb == 3) rb = 0;
  }
  // kt = NK-2
  LDB(bvn, NK - 1);
  asm volatile("s_waitcnt vmcnt(4)" ::: "memory");
  asm volatile("s_barrier" ::: "memory");
  CMP(rb);
  asm volatile("s_waitcnt lgkmcnt(0)" ::: "memory");
  asm volatile("s_barrier" ::: "memory");
  bvp[0] = bvn[0]; bvp[1] = bvn[1]; bvp[2] = bvn[2]; bvp[3] = bvn[3];
  if (++rb == 3) rb = 0;
  // kt = NK-1
  asm volatile("s_waitcnt vmcnt(0)" ::: "memory");
  asm volatile("s_barrier" ::: "memory");
  CMP(rb);
#undef STG
#undef LDB
#undef CMP

  float bv4[4];
#pragma unroll
  for (int fn = 0; fn < 4; ++fn)
    bv4[fn] = bias[e * NDIM + n0 + wn * 64 + fn * 16 + fr];

#pragma unroll
  for (int fm = 0; fm < 4; ++fm) {
#pragma unroll
    for (int j = 0; j < 4; ++j) {
      int grow = row0 + wm * 64 + fm * 16 + fq * 4 + j;
      u16* orow = Out + (size_t)grow * NDIM + n0 + wn * 64 + fr;
#pragma unroll
      for (int fn = 0; fn < 4; ++fn) {
        float v = acc[fm][fn][j] + bv4[fn];
        if (MODE == 0) v = v > 0.f ? v : 0.f;
        orow[fn * 16] = f2bf(v);
      }
    }
  }
}

// ---------------- final combine: out[n] = g0*y[s0] + g1*y[s1] ----------------

__global__ __launch_bounds__(256) void k_combine(
    const u16* __restrict__ y, const int* __restrict__ slots,
    const float* __restrict__ tok_g, float* __restrict__ out) {
  int n = blockIdx.x;
  int s0 = slots[2 * n], s1 = slots[2 * n + 1];
  float g0 = tok_g[2 * n], g1 = tok_g[2 * n + 1];
  int d = threadIdx.x * 4;
  ushort4 a = *(const ushort4*)(y + (size_t)s0 * DIM + d);
  ushort4 b = *(const ushort4*)(y + (size_t)s1 * DIM + d);
  float4 o;
  o.x = g0 * bf2f(a.x) + g1 * bf2f(b.x);
  o.y = g0 * bf2f(a.y) + g1 * bf2f(b.y);
  o.z = g0 * bf2f(a.z) + g1 * bf2f(b.z);
  o.w = g0 * bf2f(a.w) + g1 * bf2f(b.w);
  *(float4*)(out + (size_t)n * DIM + d) = o;
}

// ---------------- launch ----------------

extern "C" void kernel_launch(void* const* d_in, const int* in_sizes, int n_in,
                              void* d_out, int out_size, void* d_ws,
                              size_t ws_size, hipStream_t stream) {
  const float* x  = (const float*)d_in[0];
  const float* Wg = (const float*)d_in[1];
  const float* bg = (const float*)d_in[2];
  const float* W1 = (const float*)d_in[3];
  const float* b1 = (const float*)d_in[4];
  const float* W2 = (const float*)d_in[5];
  const float* b2 = (const float*)d_in[6];
  float* out = (float*)d_out;

  // workspace layout (bytes); total ~425 MiB.
  // y (PADROWS*DIM bf16 = 69.2 MB) reuses [0, 100663296) — xb and w1t are
  // both dead once gemm1 completes, and gemm2/combine run strictly after.
  char* w = (char*)d_ws;
  u16* xb          = (u16*)(w);                  // 33,554,432
  u16* y           = (u16*)(w);                  // 69,206,016 (after gemm1)
  u16* w1t         = (u16*)(w + 33554432);       // 67,108,864  [E][H][D]
  u16* w2t         = (u16*)(w + 100663296);      // 67,108,864  [E][D][H]
  u16* h           = (u16*)(w + 167772160);      // 276,824,064 [PADROWS][H]
  int* tok_e       = (int*)(w + 444596224);      // 131,072 (experts, then slots)
  float* tok_g     = (float*)(w + 444727296);    // 131,072
  int* counts      = (int*)(w + 444858368);
  int* cursor      = (int*)(w + 444858624);
  int* padded_off  = (int*)(w + 444858880);
  int* row2tok     = (int*)(w + 444859136);      // 135,168
  float* blocksums = (float*)(w + 445129472);    // 16,384

  k_zero<<<1, 64, 0, stream>>>(counts);
  k_gate<<<4096, 256, 0, stream>>>(x, Wg, bg, xb, tok_e, tok_g, blocksums);
  k_hist<<<16, 256, 0, stream>>>(tok_e, counts);
  k_setup<<<1, 256, 0, stream>>>(counts, blocksums, padded_off, cursor, row2tok,
                                 out + (size_t)N_TOK * DIM);
  k_scatter<<<64, 256, 0, stream>>>(tok_e, padded_off, cursor, row2tok);
  k_tcast<<<32768, 256, 0, stream>>>(W1, w1t, DIM, HID);
  k_tcast<<<32768, 256, 0, stream>>>(W2, w2t, HID, DIM);
  k_gemm<DIM, 0><<<dim3(HID / 128, MTILES), 256, 0, stream>>>(
      xb, w1t, b1, row2tok, padded_off, h);
  k_gemm<HID, 1><<<dim3(DIM / 128, MTILES), 256, 0, stream>>>(
      h, w2t, b2, row2tok, padded_off, y);
  k_combine<<<N_TOK, 256, 0, stream>>>(y, tok_e, tok_g, out);
}

// Round 12
// 1068.316 us; speedup vs baseline: 1.2798x; 1.2798x over previous
//
#include <hip/hip_runtime.h>
#include <stdint.h>

typedef unsigned short u16;
typedef __bf16 bf16x8 __attribute__((ext_vector_type(8)));
typedef float f32x4 __attribute__((ext_vector_type(4)));

#define N_TOK 16384
#define DIM   1024
#define NEXP  8
#define HID   4096
#define MTILES 264          // >= max sum of per-expert ceil(count/128) tiles
#define PADROWS 33792       // MTILES*128

__device__ __forceinline__ u16 f2bf(float f) {
  uint32_t u = __builtin_bit_cast(uint32_t, f);
  u += 0x7fffu + ((u >> 16) & 1u);   // RNE for finite values
  return (u16)(u >> 16);
}

__device__ __forceinline__ float bf2f(u16 v) {
  uint32_t u = (uint32_t)v << 16;
  return __builtin_bit_cast(float, u);
}

__device__ __forceinline__ void gload16(const void* g, void* l) {
  __builtin_amdgcn_global_load_lds(
      (const __attribute__((address_space(1))) uint32_t*)g,
      (__attribute__((address_space(3))) uint32_t*)l, 16, 0, 0);
}

// ---------------- init / transpose ----------------

__global__ void k_zero(int* counts) {
  if (threadIdx.x < NEXP) counts[threadIdx.x] = 0;
}

// src: [E][R][C] f32  ->  dst: [E][C][R] bf16
__global__ void k_tcast(const float* __restrict__ src, u16* __restrict__ dst,
                        int R, int C) {
  __shared__ float tile[32][33];
  int nc = C >> 5, nr = R >> 5;
  int t = blockIdx.x;
  int cb = t % nc; t /= nc;
  int rb = t % nr; int ee = t / nr;
  const float* s0 = src + ((size_t)ee * R + (size_t)rb * 32) * C + cb * 32;
  int tx = threadIdx.x & 31, ty = threadIdx.x >> 5;
#pragma unroll
  for (int i = 0; i < 4; ++i)
    tile[ty + i * 8][tx] = s0[(size_t)(ty + i * 8) * C + tx];
  __syncthreads();
  u16* d0 = dst + ((size_t)ee * C + (size_t)cb * 32) * R + rb * 32;
#pragma unroll
  for (int i = 0; i < 4; ++i)
    d0[(size_t)(ty + i * 8) * R + tx] = f2bf(tile[tx][ty + i * 8]);
}

// ---------------- gate (+ fused x -> bf16 cast); NO global atomics ----------

__global__ __launch_bounds__(256) void k_gate(
    const float* __restrict__ x, const float* __restrict__ Wg,
    const float* __restrict__ bg, u16* __restrict__ xb,
    int* __restrict__ tok_e, float* __restrict__ tok_g,
    float* __restrict__ blocksums) {
  __shared__ float wg_s[NEXP * DIM];   // transposed: [e][k]
  __shared__ float s4[4];
  for (int i = threadIdx.x; i < NEXP * DIM; i += 256) {
    int k = i >> 3, e = i & 7;
    wg_s[e * DIM + k] = Wg[i];
  }
  __syncthreads();
  int lane = threadIdx.x & 63, wv = threadIdx.x >> 6;
  int n = blockIdx.x * 4 + wv;
  const float4* xr4 = (const float4*)(x + (size_t)n * DIM);
  float4 xv[4];
#pragma unroll
  for (int i = 0; i < 4; ++i) xv[i] = xr4[lane + 64 * i];
  ushort4* xo4 = (ushort4*)(xb + (size_t)n * DIM);
#pragma unroll
  for (int i = 0; i < 4; ++i) {
    ushort4 p;
    p.x = f2bf(xv[i].x); p.y = f2bf(xv[i].y);
    p.z = f2bf(xv[i].z); p.w = f2bf(xv[i].w);
    xo4[lane + 64 * i] = p;
  }
  float acc[8];
#pragma unroll
  for (int e = 0; e < 8; ++e) {
    const float4* w4 = (const float4*)(wg_s + e * DIM);
    float a = 0.f;
#pragma unroll
    for (int i = 0; i < 4; ++i) {
      float4 wv4 = w4[lane + 64 * i];
      a += xv[i].x * wv4.x + xv[i].y * wv4.y + xv[i].z * wv4.z +
           xv[i].w * wv4.w;
    }
    acc[e] = a;
  }
#pragma unroll
  for (int e = 0; e < 8; ++e)
#pragma unroll
    for (int off = 32; off > 0; off >>= 1)
      acc[e] += __shfl_xor(acc[e], off);

  if (lane == 0) {
    float l0 = -1e30f, l1 = -1e30f; int e0 = 0, e1 = 0;
#pragma unroll
    for (int e = 0; e < 8; ++e) {
      float v = acc[e] + bg[e];
      if (v > l0) { l1 = l0; e1 = e0; l0 = v; e0 = e; }
      else if (v > l1) { l1 = v; e1 = e; }
    }
    // renormalized top-2 softmax gates depend only on the top-2 logits
    float g0 = 1.f / (1.f + expf(l1 - l0));
    float g1 = 1.f - g0;
    tok_e[2 * n] = e0; tok_e[2 * n + 1] = e1;
    tok_g[2 * n] = g0; tok_g[2 * n + 1] = g1;
    s4[wv] = g0;
  }
  __syncthreads();
  if (threadIdx.x == 0) blocksums[blockIdx.x] = s4[0] + s4[1] + s4[2] + s4[3];
}

// ---------------- histogram of tok_e: 16 blocks, 128 global atomics total ----

__global__ __launch_bounds__(256) void k_hist(const int* __restrict__ tok_e,
                                              int* __restrict__ counts) {
  __shared__ int lcnt[8];
  if (threadIdx.x < 8) lcnt[threadIdx.x] = 0;
  __syncthreads();
  int base4 = (blockIdx.x * 256 + threadIdx.x) * 2;   // 2x int4 = 8 entries
  const int4* t4 = (const int4*)tok_e;
  int4 a = t4[base4], b = t4[base4 + 1];
  int v[8] = {a.x, a.y, a.z, a.w, b.x, b.y, b.z, b.w};
  int c[8];
#pragma unroll
  for (int ee = 0; ee < 8; ++ee) {
    int s = 0;
#pragma unroll
    for (int i = 0; i < 8; ++i) s += (v[i] == ee);
    c[ee] = s;
  }
  int lane = threadIdx.x & 63;
#pragma unroll
  for (int ee = 0; ee < 8; ++ee) {
    int s = c[ee];
#pragma unroll
    for (int off = 32; off > 0; off >>= 1) s += __shfl_xor(s, off);
    if (lane == 0 && s) atomicAdd(&lcnt[ee], s);
  }
  __syncthreads();
  if (threadIdx.x < 8 && lcnt[threadIdx.x])
    atomicAdd(&counts[threadIdx.x], lcnt[threadIdx.x]);
}

// ---------------- routing setup (1 block) ----------------

__global__ __launch_bounds__(256) void k_setup(
    const int* __restrict__ counts, const float* __restrict__ blocksums,
    int* __restrict__ padded_off, int* __restrict__ cursor,
    int* __restrict__ row2tok, float* __restrict__ aux_out) {
  __shared__ float red[256];
  __shared__ int off_s[9];
  float s = 0.f;
  for (int i = threadIdx.x; i < 4096; i += 256) s += blocksums[i];
  red[threadIdx.x] = s;
  __syncthreads();
  for (int st = 128; st > 0; st >>= 1) {
    if (threadIdx.x < st) red[threadIdx.x] += red[threadIdx.x + st];
    __syncthreads();
  }
  if (threadIdx.x == 0) {
    int off = 0, nact = 0;
    for (int e = 0; e < 8; ++e) {
      off_s[e] = off;
      int c = counts[e];
      if (c > 0) nact++;
      off += ((c + 127) >> 7) << 7;   // pad each expert to 128-row tiles
      cursor[e] = 0;
    }
    off_s[8] = off;
    for (int e = 0; e <= 8; ++e) padded_off[e] = off_s[e];
    float m = red[0] / (float)N_TOK;
    *aux_out = (float)nact * m * m;
  }
  __syncthreads();
  // padding slots reference token 0 (valid data); no slot points at them
  for (int idx = threadIdx.x; idx < NEXP * 128; idx += 256) {
    int e = idx >> 7, i = idx & 127;
    int slot = off_s[e] + counts[e] + i;
    if (slot < off_s[e + 1]) row2tok[slot] = 0;
  }
}

// ---------------- scatter: block-aggregated; stores slots back into tok_e ----

__global__ __launch_bounds__(256) void k_scatter(
    int* __restrict__ tok_e, const int* __restrict__ padded_off,
    int* __restrict__ cursor, int* __restrict__ row2tok) {
  __shared__ int lcnt[8], lbase[8];
  if (threadIdx.x < 8) lcnt[threadIdx.x] = 0;
  __syncthreads();
  int n = blockIdx.x * 256 + threadIdx.x;
  int e0 = tok_e[2 * n], e1 = tok_e[2 * n + 1];
  int p0 = atomicAdd(&lcnt[e0], 1);
  int p1 = atomicAdd(&lcnt[e1], 1);
  __syncthreads();
  if (threadIdx.x < 8 && lcnt[threadIdx.x])
    lbase[threadIdx.x] = atomicAdd(&cursor[threadIdx.x], lcnt[threadIdx.x]);
  __syncthreads();
  int s0 = padded_off[e0] + lbase[e0] + p0;
  int s1 = padded_off[e1] + lbase[e1] + p1;
  row2tok[s0] = n;
  row2tok[s1] = n;
  tok_e[2 * n] = s0;           // tok_e now holds the slot indices
  tok_e[2 * n + 1] = s1;
}

// ---------------- grouped GEMM, 128x128 tile, BK=32 ----------------
// r9 counted-vmcnt pipeline, DOUBLE-buffered for occupancy (5 blocks/CU):
//   per iter: STG(buf^1, k+1) ; vmcnt(4) [retires stage k, k+1 in flight]
//             barrier ; CMP(k) ; lgkmcnt(0) ; barrier ; swap
// Safety: stage k+1 writes buf^1 while CMP reads buf; the trailing
// lgkmcnt(0)+barrier ensures all ds_reads of a buffer complete before any
// wave's next-iter STG overwrites it (same ledger as r8, depth-1).
// Depth-1 latency coverage is backfilled by 5 co-resident blocks (TLP).
// + chunk-XOR LDS swizzle (both-sides, rule #21) — conflicts stay 0.
// MODE 0: h = relu(gather(x) @ W1t[e] + b1)   -> bf16 rows stride HID
// MODE 1: y = h @ W2t[e] + b2                 -> bf16 rows stride DIM

template <int KDIM, int MODE>
__global__ __launch_bounds__(256, 5) void k_gemm(
    const u16* __restrict__ Asrc, const u16* __restrict__ Wt,
    const float* __restrict__ bias, const int* __restrict__ row2tok,
    const int* __restrict__ padded_off, u16* __restrict__ Out) {
  __shared__ u16 Abuf[2][4096];   // [128 rows][32 k] bf16, linear dest
  __shared__ u16 Bbuf[2][4096];   // [128 n]   [32 k] bf16, linear dest
  constexpr int NDIM = MODE ? DIM : HID;
  int row0 = blockIdx.y * 128;
  if (row0 >= padded_off[8]) return;
  int e = 0;
  while (row0 >= padded_off[e + 1]) ++e;
  int n0 = blockIdx.x * 128;
  int tid = threadIdx.x, lane = tid & 63, wv = tid >> 6;
  int wm = wv >> 1, wn = wv & 1;
  int fr = lane & 15, fq = lane >> 4;
  int ra0 = tid >> 2, ra1 = 64 + (tid >> 2);
  // pre-swizzled source chunk: physical chunk (tid&3) holds logical chunk
  // (tid&3)^((row>>1)&3); (row>>1)&3 == (tid>>3)&3 for both ra0 and ra1
  int ca = (((tid & 3) ^ ((tid >> 3) & 3))) * 8;
  const u16 *asrc0, *asrc1;
  if (MODE == 0) {
    asrc0 = Asrc + (size_t)row2tok[row0 + ra0] * KDIM + ca;
    asrc1 = Asrc + (size_t)row2tok[row0 + ra1] * KDIM + ca;
  } else {
    asrc0 = Asrc + (size_t)(row0 + ra0) * KDIM + ca;
    asrc1 = Asrc + (size_t)(row0 + ra1) * KDIM + ca;
  }
  const u16* bb = Wt + (size_t)e * (HID * DIM);
  const u16* bsrc0 = bb + (size_t)(n0 + ra0) * KDIM + ca;
  const u16* bsrc1 = bb + (size_t)(n0 + ra1) * KDIM + ca;
  int lo = wv * 512;   // wave-uniform LDS elem offset (64 lanes * 8 u16)
  // swizzled read: chunk fq of row (..+fr) is at physical fq^((fr>>1)&3)
  int sq = (fq ^ ((fr >> 1) & 3)) * 8;

  f32x4 acc[4][4];
#pragma unroll
  for (int i = 0; i < 4; ++i)
#pragma unroll
    for (int j = 0; j < 4; ++j) acc[i][j] = (f32x4){0.f, 0.f, 0.f, 0.f};
  bf16x8 av[4], bv[4];

#define STG(b, kt)                                 \
  do {                                             \
    int ko = (kt) * 32;                            \
    gload16(asrc0 + ko, &Abuf[b][lo]);             \
    gload16(asrc1 + ko, &Abuf[b][2048 + lo]);      \
    gload16(bsrc0 + ko, &Bbuf[b][lo]);             \
    gload16(bsrc1 + ko, &Bbuf[b][2048 + lo]);      \
  } while (0)

#define CMP(b)                                                                 \
  do {                                                                         \
    _Pragma("unroll") for (int fm = 0; fm < 4; ++fm)                           \
        av[fm] = *(const bf16x8*)&Abuf[b][(wm * 64 + fm * 16 + fr) * 32 + sq]; \
    _Pragma("unroll") for (int fn = 0; fn < 4; ++fn)                           \
        bv[fn] = *(const bf16x8*)&Bbuf[b][(wn * 64 + fn * 16 + fr) * 32 + sq]; \
    _Pragma("unroll") for (int fm = 0; fm < 4; ++fm)                           \
        _Pragma("unroll") for (int fn = 0; fn < 4; ++fn)                       \
            acc[fm][fn] = __builtin_amdgcn_mfma_f32_16x16x32_bf16(             \
                av[fm], bv[fn], acc[fm][fn], 0, 0, 0);                         \
  } while (0)

  constexpr int NK = KDIM / 32;
  STG(0, 0);
  int cur = 0;
  for (int kt = 0; kt < NK - 1; ++kt) {
    STG(cur ^ 1, kt + 1);
    asm volatile("s_waitcnt vmcnt(4)" ::: "memory");
    asm volatile("s_barrier" ::: "memory");
    CMP(cur);
    asm volatile("s_waitcnt lgkmcnt(0)" ::: "memory");
    asm volatile("s_barrier" ::: "memory");
    cur ^= 1;
  }
  asm volatile("s_waitcnt vmcnt(0)" ::: "memory");
  asm volatile("s_barrier" ::: "memory");
  CMP(cur);
#undef STG
#undef CMP

  float bv4[4];
#pragma unroll
  for (int fn = 0; fn < 4; ++fn)
    bv4[fn] = bias[e * NDIM + n0 + wn * 64 + fn * 16 + fr];

#pragma unroll
  for (int fm = 0; fm < 4; ++fm) {
#pragma unroll
    for (int j = 0; j < 4; ++j) {
      int grow = row0 + wm * 64 + fm * 16 + fq * 4 + j;
      u16* orow = Out + (size_t)grow * NDIM + n0 + wn * 64 + fr;
#pragma unroll
      for (int fn = 0; fn < 4; ++fn) {
        float v = acc[fm][fn][j] + bv4[fn];
        if (MODE == 0) v = v > 0.f ? v : 0.f;
        orow[fn * 16] = f2bf(v);
      }
    }
  }
}

// ---------------- final combine: out[n] = g0*y[s0] + g1*y[s1] ----------------

__global__ __launch_bounds__(256) void k_combine(
    const u16* __restrict__ y, const int* __restrict__ slots,
    const float* __restrict__ tok_g, float* __restrict__ out) {
  int n = blockIdx.x;
  int s0 = slots[2 * n], s1 = slots[2 * n + 1];
  float g0 = tok_g[2 * n], g1 = tok_g[2 * n + 1];
  int d = threadIdx.x * 4;
  ushort4 a = *(const ushort4*)(y + (size_t)s0 * DIM + d);
  ushort4 b = *(const ushort4*)(y + (size_t)s1 * DIM + d);
  float4 o;
  o.x = g0 * bf2f(a.x) + g1 * bf2f(b.x);
  o.y = g0 * bf2f(a.y) + g1 * bf2f(b.y);
  o.z = g0 * bf2f(a.z) + g1 * bf2f(b.z);
  o.w = g0 * bf2f(a.w) + g1 * bf2f(b.w);
  *(float4*)(out + (size_t)n * DIM + d) = o;
}

// ---------------- launch ----------------

extern "C" void kernel_launch(void* const* d_in, const int* in_sizes, int n_in,
                              void* d_out, int out_size, void* d_ws,
                              size_t ws_size, hipStream_t stream) {
  const float* x  = (const float*)d_in[0];
  const float* Wg = (const float*)d_in[1];
  const float* bg = (const float*)d_in[2];
  const float* W1 = (const float*)d_in[3];
  const float* b1 = (const float*)d_in[4];
  const float* W2 = (const float*)d_in[5];
  const float* b2 = (const float*)d_in[6];
  float* out = (float*)d_out;

  // workspace layout (bytes); total ~425 MiB.
  // y (PADROWS*DIM bf16 = 69.2 MB) reuses [0, 100663296) — xb and w1t are
  // both dead once gemm1 completes, and gemm2/combine run strictly after.
  char* w = (char*)d_ws;
  u16* xb          = (u16*)(w);                  // 33,554,432
  u16* y           = (u16*)(w);                  // 69,206,016 (after gemm1)
  u16* w1t         = (u16*)(w + 33554432);       // 67,108,864  [E][H][D]
  u16* w2t         = (u16*)(w + 100663296);      // 67,108,864  [E][D][H]
  u16* h           = (u16*)(w + 167772160);      // 276,824,064 [PADROWS][H]
  int* tok_e       = (int*)(w + 444596224);      // 131,072 (experts, then slots)
  float* tok_g     = (float*)(w + 444727296);    // 131,072
  int* counts      = (int*)(w + 444858368);
  int* cursor      = (int*)(w + 444858624);
  int* padded_off  = (int*)(w + 444858880);
  int* row2tok     = (int*)(w + 444859136);      // 135,168
  float* blocksums = (float*)(w + 445129472);    // 16,384

  k_zero<<<1, 64, 0, stream>>>(counts);
  k_gate<<<4096, 256, 0, stream>>>(x, Wg, bg, xb, tok_e, tok_g, blocksums);
  k_hist<<<16, 256, 0, stream>>>(tok_e, counts);
  k_setup<<<1, 256, 0, stream>>>(counts, blocksums, padded_off, cursor, row2tok,
                                 out + (size_t)N_TOK * DIM);
  k_scatter<<<64, 256, 0, stream>>>(tok_e, padded_off, cursor, row2tok);
  k_tcast<<<32768, 256, 0, stream>>>(W1, w1t, DIM, HID);
  k_tcast<<<32768, 256, 0, stream>>>(W2, w2t, HID, DIM);
  k_gemm<DIM, 0><<<dim3(HID / 128, MTILES), 256, 0, stream>>>(
      xb, w1t, b1, row2tok, padded_off, h);
  k_gemm<HID, 1><<<dim3(DIM / 128, MTILES), 256, 0, stream>>>(
      h, w2t, b2, row2tok, padded_off, y);
  k_combine<<<N_TOK, 256, 0, stream>>>(y, tok_e, tok_g, out);
}

// Round 14
// 874.921 us; speedup vs baseline: 1.5627x; 1.2210x over previous
//
#include <hip/hip_runtime.h>
#include <stdint.h>

typedef unsigned short u16;
typedef __bf16 bf16x8 __attribute__((ext_vector_type(8)));
typedef float f32x4 __attribute__((ext_vector_type(4)));

#define N_TOK 16384
#define DIM   1024
#define NEXP  8
#define HID   4096
#define MTILES 264          // row-tiles incl. padding; divisible by 8
#define PADROWS 33792       // MTILES*128

__device__ __forceinline__ u16 f2bf(float f) {
  uint32_t u = __builtin_bit_cast(uint32_t, f);
  u += 0x7fffu + ((u >> 16) & 1u);   // RNE for finite values
  return (u16)(u >> 16);
}

__device__ __forceinline__ float bf2f(u16 v) {
  uint32_t u = (uint32_t)v << 16;
  return __builtin_bit_cast(float, u);
}

__device__ __forceinline__ void gload16(const void* g, void* l) {
  __builtin_amdgcn_global_load_lds(
      (const __attribute__((address_space(1))) uint32_t*)g,
      (__attribute__((address_space(3))) uint32_t*)l, 16, 0, 0);
}

// ---------------- init / transpose ----------------

__global__ void k_zero(int* counts) {
  if (threadIdx.x < NEXP) counts[threadIdx.x] = 0;
}

// src: [E][R][C] f32  ->  dst: [E][C][R] bf16
__global__ void k_tcast(const float* __restrict__ src, u16* __restrict__ dst,
                        int R, int C) {
  __shared__ float tile[32][33];
  int nc = C >> 5, nr = R >> 5;
  int t = blockIdx.x;
  int cb = t % nc; t /= nc;
  int rb = t % nr; int ee = t / nr;
  const float* s0 = src + ((size_t)ee * R + (size_t)rb * 32) * C + cb * 32;
  int tx = threadIdx.x & 31, ty = threadIdx.x >> 5;
#pragma unroll
  for (int i = 0; i < 4; ++i)
    tile[ty + i * 8][tx] = s0[(size_t)(ty + i * 8) * C + tx];
  __syncthreads();
  u16* d0 = dst + ((size_t)ee * C + (size_t)cb * 32) * R + rb * 32;
#pragma unroll
  for (int i = 0; i < 4; ++i)
    d0[(size_t)(ty + i * 8) * R + tx] = f2bf(tile[tx][ty + i * 8]);
}

// ---------------- gate (+ fused x -> bf16 cast); NO global atomics ----------

__global__ __launch_bounds__(256) void k_gate(
    const float* __restrict__ x, const float* __restrict__ Wg,
    const float* __restrict__ bg, u16* __restrict__ xb,
    int* __restrict__ tok_e, float* __restrict__ tok_g,
    float* __restrict__ blocksums) {
  __shared__ float wg_s[NEXP * DIM];   // transposed: [e][k]
  __shared__ float s4[4];
  for (int i = threadIdx.x; i < NEXP * DIM; i += 256) {
    int k = i >> 3, e = i & 7;
    wg_s[e * DIM + k] = Wg[i];
  }
  __syncthreads();
  int lane = threadIdx.x & 63, wv = threadIdx.x >> 6;
  int n = blockIdx.x * 4 + wv;
  const float4* xr4 = (const float4*)(x + (size_t)n * DIM);
  float4 xv[4];
#pragma unroll
  for (int i = 0; i < 4; ++i) xv[i] = xr4[lane + 64 * i];
  ushort4* xo4 = (ushort4*)(xb + (size_t)n * DIM);
#pragma unroll
  for (int i = 0; i < 4; ++i) {
    ushort4 p;
    p.x = f2bf(xv[i].x); p.y = f2bf(xv[i].y);
    p.z = f2bf(xv[i].z); p.w = f2bf(xv[i].w);
    xo4[lane + 64 * i] = p;
  }
  float acc[8];
#pragma unroll
  for (int e = 0; e < 8; ++e) {
    const float4* w4 = (const float4*)(wg_s + e * DIM);
    float a = 0.f;
#pragma unroll
    for (int i = 0; i < 4; ++i) {
      float4 wv4 = w4[lane + 64 * i];
      a += xv[i].x * wv4.x + xv[i].y * wv4.y + xv[i].z * wv4.z +
           xv[i].w * wv4.w;
    }
    acc[e] = a;
  }
#pragma unroll
  for (int e = 0; e < 8; ++e)
#pragma unroll
    for (int off = 32; off > 0; off >>= 1)
      acc[e] += __shfl_xor(acc[e], off);

  if (lane == 0) {
    float l0 = -1e30f, l1 = -1e30f; int e0 = 0, e1 = 0;
#pragma unroll
    for (int e = 0; e < 8; ++e) {
      float v = acc[e] + bg[e];
      if (v > l0) { l1 = l0; e1 = e0; l0 = v; e0 = e; }
      else if (v > l1) { l1 = v; e1 = e; }
    }
    // renormalized top-2 softmax gates depend only on the top-2 logits
    float g0 = 1.f / (1.f + expf(l1 - l0));
    float g1 = 1.f - g0;
    tok_e[2 * n] = e0; tok_e[2 * n + 1] = e1;
    tok_g[2 * n] = g0; tok_g[2 * n + 1] = g1;
    s4[wv] = g0;
  }
  __syncthreads();
  if (threadIdx.x == 0) blocksums[blockIdx.x] = s4[0] + s4[1] + s4[2] + s4[3];
}

// ---------------- histogram of tok_e: 16 blocks, 128 global atomics total ----

__global__ __launch_bounds__(256) void k_hist(const int* __restrict__ tok_e,
                                              int* __restrict__ counts) {
  __shared__ int lcnt[8];
  if (threadIdx.x < 8) lcnt[threadIdx.x] = 0;
  __syncthreads();
  int base4 = (blockIdx.x * 256 + threadIdx.x) * 2;   // 2x int4 = 8 entries
  const int4* t4 = (const int4*)tok_e;
  int4 a = t4[base4], b = t4[base4 + 1];
  int v[8] = {a.x, a.y, a.z, a.w, b.x, b.y, b.z, b.w};
  int c[8];
#pragma unroll
  for (int ee = 0; ee < 8; ++ee) {
    int s = 0;
#pragma unroll
    for (int i = 0; i < 8; ++i) s += (v[i] == ee);
    c[ee] = s;
  }
  int lane = threadIdx.x & 63;
#pragma unroll
  for (int ee = 0; ee < 8; ++ee) {
    int s = c[ee];
#pragma unroll
    for (int off = 32; off > 0; off >>= 1) s += __shfl_xor(s, off);
    if (lane == 0 && s) atomicAdd(&lcnt[ee], s);
  }
  __syncthreads();
  if (threadIdx.x < 8 && lcnt[threadIdx.x])
    atomicAdd(&counts[threadIdx.x], lcnt[threadIdx.x]);
}

// ---------------- routing setup (1 block) ----------------

__global__ __launch_bounds__(256) void k_setup(
    const int* __restrict__ counts, const float* __restrict__ blocksums,
    int* __restrict__ padded_off, int* __restrict__ cursor,
    int* __restrict__ row2tok, float* __restrict__ aux_out) {
  __shared__ float red[256];
  __shared__ int off_s[9];
  float s = 0.f;
  for (int i = threadIdx.x; i < 4096; i += 256) s += blocksums[i];
  red[threadIdx.x] = s;
  __syncthreads();
  for (int st = 128; st > 0; st >>= 1) {
    if (threadIdx.x < st) red[threadIdx.x] += red[threadIdx.x + st];
    __syncthreads();
  }
  if (threadIdx.x == 0) {
    int off = 0, nact = 0;
    for (int e = 0; e < 8; ++e) {
      off_s[e] = off;
      int c = counts[e];
      if (c > 0) nact++;
      off += ((c + 127) >> 7) << 7;   // pad each expert to 128-row tiles
      cursor[e] = 0;
    }
    off_s[8] = off;
    for (int e = 0; e <= 8; ++e) padded_off[e] = off_s[e];
    float m = red[0] / (float)N_TOK;
    *aux_out = (float)nact * m * m;
  }
  __syncthreads();
  // padding slots reference token 0 (valid data); no slot points at them
  for (int idx = threadIdx.x; idx < NEXP * 128; idx += 256) {
    int e = idx >> 7, i = idx & 127;
    int slot = off_s[e] + counts[e] + i;
    if (slot < off_s[e + 1]) row2tok[slot] = 0;
  }
}

// ---------------- scatter: block-aggregated; stores slots back into tok_e ----

__global__ __launch_bounds__(256) void k_scatter(
    int* __restrict__ tok_e, const int* __restrict__ padded_off,
    int* __restrict__ cursor, int* __restrict__ row2tok) {
  __shared__ int lcnt[8], lbase[8];
  if (threadIdx.x < 8) lcnt[threadIdx.x] = 0;
  __syncthreads();
  int n = blockIdx.x * 256 + threadIdx.x;
  int e0 = tok_e[2 * n], e1 = tok_e[2 * n + 1];
  int p0 = atomicAdd(&lcnt[e0], 1);
  int p1 = atomicAdd(&lcnt[e1], 1);
  __syncthreads();
  if (threadIdx.x < 8 && lcnt[threadIdx.x])
    lbase[threadIdx.x] = atomicAdd(&cursor[threadIdx.x], lcnt[threadIdx.x]);
  __syncthreads();
  int s0 = padded_off[e0] + lbase[e0] + p0;
  int s1 = padded_off[e1] + lbase[e1] + p1;
  row2tok[s0] = n;
  row2tok[s1] = n;
  tok_e[2 * n] = s0;           // tok_e now holds the slot indices
  tok_e[2 * n + 1] = s1;
}

// ---------------- grouped GEMM, 128x128 tile, BK=32 ----------------
// r9 proven pipeline: triple-buffered LDS, 2-deep prefetch, counted vmcnt:
//   per iter: STG(k+2) ; vmcnt(8) ; barrier ; CMP(k) ; lgkmcnt(0) ; barrier
// + chunk-XOR LDS swizzle (both-sides, rule #21) — bank conflicts = 0.
// XCD-grouped dispatch (r13, decode FIXED r14): 1-D grid; HW round-robins
// d%8 -> XCD. Decode so ALL n-siblings of a row-tile have d = same (mod 8)
// and sit in one 8*NT dispatch window: same XCD + concurrent -> the shared
// A-panel is fetched into that XCD's L2 once, served NT times from L2.
//   d = 8*(rgroup*NT + n_t) + xcd ; row-tile = rgroup*8 + xcd ; NT = 1<<NTL
// COVERAGE: grid must be 8 * NT * ceil(MTILES/8), NT = (NDIM/128). r13 bug:
// gemm1 used NTL=4 (NT=16) with 32 n-tiles -> half of h never written.
// gemm1: NTL=5 (32 n-tiles). gemm2: NTL=3 (8 n-tiles).
// MODE 0: h = relu(gather(x) @ W1t[e] + b1)   -> bf16 rows stride HID
// MODE 1: y = h @ W2t[e] + b2                 -> bf16 rows stride DIM

template <int KDIM, int MODE, int NTL>
__global__ __launch_bounds__(256, 3) void k_gemm(
    const u16* __restrict__ Asrc, const u16* __restrict__ Wt,
    const float* __restrict__ bias, const int* __restrict__ row2tok,
    const int* __restrict__ padded_off, u16* __restrict__ Out) {
  __shared__ u16 Abuf[3][4096];   // [128 rows][32 k] bf16, linear dest
  __shared__ u16 Bbuf[3][4096];   // [128 n]   [32 k] bf16, linear dest
  constexpr int NDIM = MODE ? DIM : HID;
  static_assert((1 << NTL) == NDIM / 128, "NT must equal n-tile count");
  int d = blockIdx.x;
  int xcd = d & 7;
  int n_t = (d >> 3) & ((1 << NTL) - 1);
  int rg  = d >> (3 + NTL);
  int row0 = (rg * 8 + xcd) * 128;
  if (row0 >= padded_off[8]) return;
  int e = 0;
  while (row0 >= padded_off[e + 1]) ++e;
  int n0 = n_t * 128;
  int tid = threadIdx.x, lane = tid & 63, wv = tid >> 6;
  int wm = wv >> 1, wn = wv & 1;
  int fr = lane & 15, fq = lane >> 4;
  int ra0 = tid >> 2, ra1 = 64 + (tid >> 2);
  // pre-swizzled source chunk: physical chunk (tid&3) holds logical chunk
  // (tid&3)^((row>>1)&3); (row>>1)&3 == (tid>>3)&3 for both ra0 and ra1
  int ca = (((tid & 3) ^ ((tid >> 3) & 3))) * 8;
  const u16 *asrc0, *asrc1;
  if (MODE == 0) {
    asrc0 = Asrc + (size_t)row2tok[row0 + ra0] * KDIM + ca;
    asrc1 = Asrc + (size_t)row2tok[row0 + ra1] * KDIM + ca;
  } else {
    asrc0 = Asrc + (size_t)(row0 + ra0) * KDIM + ca;
    asrc1 = Asrc + (size_t)(row0 + ra1) * KDIM + ca;
  }
  const u16* bb = Wt + (size_t)e * (HID * DIM);
  const u16* bsrc0 = bb + (size_t)(n0 + ra0) * KDIM + ca;
  const u16* bsrc1 = bb + (size_t)(n0 + ra1) * KDIM + ca;
  int lo = wv * 512;   // wave-uniform LDS elem offset (64 lanes * 8 u16)
  // swizzled read: chunk fq of row (..+fr) is at physical fq^((fr>>1)&3)
  int sq = (fq ^ ((fr >> 1) & 3)) * 8;

  f32x4 acc[4][4];
#pragma unroll
  for (int i = 0; i < 4; ++i)
#pragma unroll
    for (int j = 0; j < 4; ++j) acc[i][j] = (f32x4){0.f, 0.f, 0.f, 0.f};
  bf16x8 av[4], bv[4];

#define STG(b, kt)                                 \
  do {                                             \
    int ko = (kt) * 32;                            \
    gload16(asrc0 + ko, &Abuf[b][lo]);             \
    gload16(asrc1 + ko, &Abuf[b][2048 + lo]);      \
    gload16(bsrc0 + ko, &Bbuf[b][lo]);             \
    gload16(bsrc1 + ko, &Bbuf[b][2048 + lo]);      \
  } while (0)

#define CMP(b)                                                                 \
  do {                                                                         \
    _Pragma("unroll") for (int fm = 0; fm < 4; ++fm)                           \
        av[fm] = *(const bf16x8*)&Abuf[b][(wm * 64 + fm * 16 + fr) * 32 + sq]; \
    _Pragma("unroll") for (int fn = 0; fn < 4; ++fn)                           \
        bv[fn] = *(const bf16x8*)&Bbuf[b][(wn * 64 + fn * 16 + fr) * 32 + sq]; \
    _Pragma("unroll") for (int fm = 0; fm < 4; ++fm)                           \
        _Pragma("unroll") for (int fn = 0; fn < 4; ++fn)                       \
            acc[fm][fn] = __builtin_amdgcn_mfma_f32_16x16x32_bf16(             \
                av[fm], bv[fn], acc[fm][fn], 0, 0, 0);                         \
  } while (0)

  constexpr int NK = KDIM / 32;
  STG(0, 0);
  STG(1, 1);
  int rb = 0;
  for (int kt = 0; kt < NK - 2; ++kt) {
    int sb = rb + 2; if (sb >= 3) sb -= 3;
    STG(sb, kt + 2);
    asm volatile("s_waitcnt vmcnt(8)" ::: "memory");
    asm volatile("s_barrier" ::: "memory");
    CMP(rb);
    asm volatile("s_waitcnt lgkmcnt(0)" ::: "memory");
    asm volatile("s_barrier" ::: "memory");
    if (++rb == 3) rb = 0;
  }
  asm volatile("s_waitcnt vmcnt(4)" ::: "memory");
  asm volatile("s_barrier" ::: "memory");
  CMP(rb);
  if (++rb == 3) rb = 0;
  asm volatile("s_waitcnt vmcnt(0)" ::: "memory");
  asm volatile("s_barrier" ::: "memory");
  CMP(rb);
#undef STG
#undef CMP

  float bv4[4];
#pragma unroll
  for (int fn = 0; fn < 4; ++fn)
    bv4[fn] = bias[e * NDIM + n0 + wn * 64 + fn * 16 + fr];

#pragma unroll
  for (int fm = 0; fm < 4; ++fm) {
#pragma unroll
    for (int j = 0; j < 4; ++j) {
      int grow = row0 + wm * 64 + fm * 16 + fq * 4 + j;
      u16* orow = Out + (size_t)grow * NDIM + n0 + wn * 64 + fr;
#pragma unroll
      for (int fn = 0; fn < 4; ++fn) {
        float v = acc[fm][fn][j] + bv4[fn];
        if (MODE == 0) v = v > 0.f ? v : 0.f;
        orow[fn * 16] = f2bf(v);
      }
    }
  }
}

// ---------------- final combine: out[n] = g0*y[s0] + g1*y[s1] ----------------

__global__ __launch_bounds__(256) void k_combine(
    const u16* __restrict__ y, const int* __restrict__ slots,
    const float* __restrict__ tok_g, float* __restrict__ out) {
  int n = blockIdx.x;
  int s0 = slots[2 * n], s1 = slots[2 * n + 1];
  float g0 = tok_g[2 * n], g1 = tok_g[2 * n + 1];
  int d = threadIdx.x * 4;
  ushort4 a = *(const ushort4*)(y + (size_t)s0 * DIM + d);
  ushort4 b = *(const ushort4*)(y + (size_t)s1 * DIM + d);
  float4 o;
  o.x = g0 * bf2f(a.x) + g1 * bf2f(b.x);
  o.y = g0 * bf2f(a.y) + g1 * bf2f(b.y);
  o.z = g0 * bf2f(a.z) + g1 * bf2f(b.z);
  o.w = g0 * bf2f(a.w) + g1 * bf2f(b.w);
  *(float4*)(out + (size_t)n * DIM + d) = o;
}

// ---------------- launch ----------------

extern "C" void kernel_launch(void* const* d_in, const int* in_sizes, int n_in,
                              void* d_out, int out_size, void* d_ws,
                              size_t ws_size, hipStream_t stream) {
  const float* x  = (const float*)d_in[0];
  const float* Wg = (const float*)d_in[1];
  const float* bg = (const float*)d_in[2];
  const float* W1 = (const float*)d_in[3];
  const float* b1 = (const float*)d_in[4];
  const float* W2 = (const float*)d_in[5];
  const float* b2 = (const float*)d_in[6];
  float* out = (float*)d_out;

  // workspace layout (bytes); total ~425 MiB.
  // y (PADROWS*DIM bf16 = 69.2 MB) reuses [0, 100663296) — xb and w1t are
  // both dead once gemm1 completes, and gemm2/combine run strictly after.
  char* w = (char*)d_ws;
  u16* xb          = (u16*)(w);                  // 33,554,432
  u16* y           = (u16*)(w);                  // 69,206,016 (after gemm1)
  u16* w1t         = (u16*)(w + 33554432);       // 67,108,864  [E][H][D]
  u16* w2t         = (u16*)(w + 100663296);      // 67,108,864  [E][D][H]
  u16* h           = (u16*)(w + 167772160);      // 276,824,064 [PADROWS][H]
  int* tok_e       = (int*)(w + 444596224);      // 131,072 (experts, then slots)
  float* tok_g     = (float*)(w + 444727296);    // 131,072
  int* counts      = (int*)(w + 444858368);
  int* cursor      = (int*)(w + 444858624);
  int* padded_off  = (int*)(w + 444858880);
  int* row2tok     = (int*)(w + 444859136);      // 135,168
  float* blocksums = (float*)(w + 445129472);    // 16,384

  k_zero<<<1, 64, 0, stream>>>(counts);
  k_gate<<<4096, 256, 0, stream>>>(x, Wg, bg, xb, tok_e, tok_g, blocksums);
  k_hist<<<16, 256, 0, stream>>>(tok_e, counts);
  k_setup<<<1, 256, 0, stream>>>(counts, blocksums, padded_off, cursor, row2tok,
                                 out + (size_t)N_TOK * DIM);
  k_scatter<<<64, 256, 0, stream>>>(tok_e, padded_off, cursor, row2tok);
  k_tcast<<<32768, 256, 0, stream>>>(W1, w1t, DIM, HID);
  k_tcast<<<32768, 256, 0, stream>>>(W2, w2t, HID, DIM);
  // XCD-grouped 1-D grids: 8 * NT * (MTILES/8) blocks; NT = NDIM/128
  k_gemm<DIM, 0, 5><<<MTILES * (HID / 128), 256, 0, stream>>>(
      xb, w1t, b1, row2tok, padded_off, h);
  k_gemm<HID, 1, 3><<<MTILES * (DIM / 128), 256, 0, stream>>>(
      h, w2t, b2, row2tok, padded_off, y);
  k_combine<<<N_TOK, 256, 0, stream>>>(y, tok_e, tok_g, out);
}

// Round 15
// 848.531 us; speedup vs baseline: 1.6113x; 1.0311x over previous
//
#include <hip/hip_runtime.h>
#include <stdint.h>

typedef unsigned short u16;
typedef __bf16 bf16x8 __attribute__((ext_vector_type(8)));
typedef float f32x4 __attribute__((ext_vector_type(4)));

#define N_TOK 16384
#define DIM   1024
#define NEXP  8
#define HID   4096
#define MTILES 264          // row-tiles incl. padding; divisible by 8
#define PADROWS 33792       // MTILES*128

__device__ __forceinline__ u16 f2bf(float f) {
  uint32_t u = __builtin_bit_cast(uint32_t, f);
  u += 0x7fffu + ((u >> 16) & 1u);   // RNE for finite values
  return (u16)(u >> 16);
}

__device__ __forceinline__ float bf2f(u16 v) {
  uint32_t u = (uint32_t)v << 16;
  return __builtin_bit_cast(float, u);
}

__device__ __forceinline__ void gload16(const void* g, void* l) {
  __builtin_amdgcn_global_load_lds(
      (const __attribute__((address_space(1))) uint32_t*)g,
      (__attribute__((address_space(3))) uint32_t*)l, 16, 0, 0);
}

// ---------------- init / transpose ----------------

__global__ void k_zero(int* counts) {
  if (threadIdx.x < NEXP) counts[threadIdx.x] = 0;
}

// src: [E][R][C] f32  ->  dst: [E][C][R] bf16
__global__ void k_tcast(const float* __restrict__ src, u16* __restrict__ dst,
                        int R, int C) {
  __shared__ float tile[32][33];
  int nc = C >> 5, nr = R >> 5;
  int t = blockIdx.x;
  int cb = t % nc; t /= nc;
  int rb = t % nr; int ee = t / nr;
  const float* s0 = src + ((size_t)ee * R + (size_t)rb * 32) * C + cb * 32;
  int tx = threadIdx.x & 31, ty = threadIdx.x >> 5;
#pragma unroll
  for (int i = 0; i < 4; ++i)
    tile[ty + i * 8][tx] = s0[(size_t)(ty + i * 8) * C + tx];
  __syncthreads();
  u16* d0 = dst + ((size_t)ee * C + (size_t)cb * 32) * R + rb * 32;
#pragma unroll
  for (int i = 0; i < 4; ++i)
    d0[(size_t)(ty + i * 8) * R + tx] = f2bf(tile[tx][ty + i * 8]);
}

// ---------------- gate (+ fused x -> bf16 cast); NO global atomics ----------

__global__ __launch_bounds__(256) void k_gate(
    const float* __restrict__ x, const float* __restrict__ Wg,
    const float* __restrict__ bg, u16* __restrict__ xb,
    int* __restrict__ tok_e, float* __restrict__ tok_g,
    float* __restrict__ blocksums) {
  __shared__ float wg_s[NEXP * DIM];   // transposed: [e][k]
  __shared__ float s4[4];
  for (int i = threadIdx.x; i < NEXP * DIM; i += 256) {
    int k = i >> 3, e = i & 7;
    wg_s[e * DIM + k] = Wg[i];
  }
  __syncthreads();
  int lane = threadIdx.x & 63, wv = threadIdx.x >> 6;
  int n = blockIdx.x * 4 + wv;
  const float4* xr4 = (const float4*)(x + (size_t)n * DIM);
  float4 xv[4];
#pragma unroll
  for (int i = 0; i < 4; ++i) xv[i] = xr4[lane + 64 * i];
  ushort4* xo4 = (ushort4*)(xb + (size_t)n * DIM);
#pragma unroll
  for (int i = 0; i < 4; ++i) {
    ushort4 p;
    p.x = f2bf(xv[i].x); p.y = f2bf(xv[i].y);
    p.z = f2bf(xv[i].z); p.w = f2bf(xv[i].w);
    xo4[lane + 64 * i] = p;
  }
  float acc[8];
#pragma unroll
  for (int e = 0; e < 8; ++e) {
    const float4* w4 = (const float4*)(wg_s + e * DIM);
    float a = 0.f;
#pragma unroll
    for (int i = 0; i < 4; ++i) {
      float4 wv4 = w4[lane + 64 * i];
      a += xv[i].x * wv4.x + xv[i].y * wv4.y + xv[i].z * wv4.z +
           xv[i].w * wv4.w;
    }
    acc[e] = a;
  }
#pragma unroll
  for (int e = 0; e < 8; ++e)
#pragma unroll
    for (int off = 32; off > 0; off >>= 1)
      acc[e] += __shfl_xor(acc[e], off);

  if (lane == 0) {
    float l0 = -1e30f, l1 = -1e30f; int e0 = 0, e1 = 0;
#pragma unroll
    for (int e = 0; e < 8; ++e) {
      float v = acc[e] + bg[e];
      if (v > l0) { l1 = l0; e1 = e0; l0 = v; e0 = e; }
      else if (v > l1) { l1 = v; e1 = e; }
    }
    // renormalized top-2 softmax gates depend only on the top-2 logits
    float g0 = 1.f / (1.f + expf(l1 - l0));
    float g1 = 1.f - g0;
    tok_e[2 * n] = e0; tok_e[2 * n + 1] = e1;
    tok_g[2 * n] = g0; tok_g[2 * n + 1] = g1;
    s4[wv] = g0;
  }
  __syncthreads();
  if (threadIdx.x == 0) blocksums[blockIdx.x] = s4[0] + s4[1] + s4[2] + s4[3];
}

// ---------------- histogram of tok_e: 16 blocks, 128 global atomics total ----

__global__ __launch_bounds__(256) void k_hist(const int* __restrict__ tok_e,
                                              int* __restrict__ counts) {
  __shared__ int lcnt[8];
  if (threadIdx.x < 8) lcnt[threadIdx.x] = 0;
  __syncthreads();
  int base4 = (blockIdx.x * 256 + threadIdx.x) * 2;   // 2x int4 = 8 entries
  const int4* t4 = (const int4*)tok_e;
  int4 a = t4[base4], b = t4[base4 + 1];
  int v[8] = {a.x, a.y, a.z, a.w, b.x, b.y, b.z, b.w};
  int c[8];
#pragma unroll
  for (int ee = 0; ee < 8; ++ee) {
    int s = 0;
#pragma unroll
    for (int i = 0; i < 8; ++i) s += (v[i] == ee);
    c[ee] = s;
  }
  int lane = threadIdx.x & 63;
#pragma unroll
  for (int ee = 0; ee < 8; ++ee) {
    int s = c[ee];
#pragma unroll
    for (int off = 32; off > 0; off >>= 1) s += __shfl_xor(s, off);
    if (lane == 0 && s) atomicAdd(&lcnt[ee], s);
  }
  __syncthreads();
  if (threadIdx.x < 8 && lcnt[threadIdx.x])
    atomicAdd(&counts[threadIdx.x], lcnt[threadIdx.x]);
}

// ---------------- routing setup (1 block) ----------------

__global__ __launch_bounds__(256) void k_setup(
    const int* __restrict__ counts, const float* __restrict__ blocksums,
    int* __restrict__ padded_off, int* __restrict__ cursor,
    int* __restrict__ row2tok, float* __restrict__ aux_out) {
  __shared__ float red[256];
  __shared__ int off_s[9];
  float s = 0.f;
  for (int i = threadIdx.x; i < 4096; i += 256) s += blocksums[i];
  red[threadIdx.x] = s;
  __syncthreads();
  for (int st = 128; st > 0; st >>= 1) {
    if (threadIdx.x < st) red[threadIdx.x] += red[threadIdx.x + st];
    __syncthreads();
  }
  if (threadIdx.x == 0) {
    int off = 0, nact = 0;
    for (int e = 0; e < 8; ++e) {
      off_s[e] = off;
      int c = counts[e];
      if (c > 0) nact++;
      off += ((c + 127) >> 7) << 7;   // pad each expert to 128-row tiles
      cursor[e] = 0;
    }
    off_s[8] = off;
    for (int e = 0; e <= 8; ++e) padded_off[e] = off_s[e];
    float m = red[0] / (float)N_TOK;
    *aux_out = (float)nact * m * m;
  }
  __syncthreads();
  // padding slots reference token 0 (valid data); no slot points at them
  for (int idx = threadIdx.x; idx < NEXP * 128; idx += 256) {
    int e = idx >> 7, i = idx & 127;
    int slot = off_s[e] + counts[e] + i;
    if (slot < off_s[e + 1]) row2tok[slot] = 0;
  }
}

// ---------------- scatter: block-aggregated; stores slots back into tok_e ----

__global__ __launch_bounds__(256) void k_scatter(
    int* __restrict__ tok_e, const int* __restrict__ padded_off,
    int* __restrict__ cursor, int* __restrict__ row2tok) {
  __shared__ int lcnt[8], lbase[8];
  if (threadIdx.x < 8) lcnt[threadIdx.x] = 0;
  __syncthreads();
  int n = blockIdx.x * 256 + threadIdx.x;
  int e0 = tok_e[2 * n], e1 = tok_e[2 * n + 1];
  int p0 = atomicAdd(&lcnt[e0], 1);
  int p1 = atomicAdd(&lcnt[e1], 1);
  __syncthreads();
  if (threadIdx.x < 8 && lcnt[threadIdx.x])
    lbase[threadIdx.x] = atomicAdd(&cursor[threadIdx.x], lcnt[threadIdx.x]);
  __syncthreads();
  int s0 = padded_off[e0] + lbase[e0] + p0;
  int s1 = padded_off[e1] + lbase[e1] + p1;
  row2tok[s0] = n;
  row2tok[s1] = n;
  tok_e[2 * n] = s0;           // tok_e now holds the slot indices
  tok_e[2 * n + 1] = s1;
}

// ---------------- grouped GEMM, 128x128 tile, BK=32 ----------------
// r9 proven pipeline: triple-buffered LDS, 2-deep prefetch, counted vmcnt:
//   per iter: STG(k+2) ; vmcnt(8) ; barrier ; CMP(k) ; lgkmcnt(0) ; barrier
// + chunk-XOR LDS swizzle (both-sides, rule #21) — bank conflicts = 0.
//
// Per-GEMM dispatch mapping (r15 — mechanism measured r9 vs r14):
//  GRID2D=1 (gemm1): 2-D grid, n fastest. XCD = linear%8 = n_t%8 -> each XCD
//    owns a fixed set of 4 B-panels (4 MB = its L2), reused across ALL
//    row-tiles. gemm1 is B-L2-reuse-bound (A-source xb is L3-resident).
//  GRID2D=0 (gemm2): 1-D XCD-grouped: d = 8*(rg*NT + n_t) + xcd,
//    row-tile = rg*8+xcd. All n-siblings of a row-tile on ONE XCD,
//    concurrent -> shared 1 MB h-panel fetched once into L2 (h = 277 MB
//    overflows L3; A-reuse is gemm2's binding constraint; r14: -70 µs).
// MODE 0: h = relu(gather(x) @ W1t[e] + b1)   -> bf16 rows stride HID
// MODE 1: y = h @ W2t[e] + b2                 -> bf16 rows stride DIM

template <int KDIM, int MODE, int NTL, int GRID2D>
__global__ __launch_bounds__(256, 3) void k_gemm(
    const u16* __restrict__ Asrc, const u16* __restrict__ Wt,
    const float* __restrict__ bias, const int* __restrict__ row2tok,
    const int* __restrict__ padded_off, u16* __restrict__ Out) {
  __shared__ u16 Abuf[3][4096];   // [128 rows][32 k] bf16, linear dest
  __shared__ u16 Bbuf[3][4096];   // [128 n]   [32 k] bf16, linear dest
  constexpr int NDIM = MODE ? DIM : HID;
  static_assert(GRID2D || (1 << NTL) == NDIM / 128, "NT must cover n-tiles");
  int row0, n0;
  if (GRID2D) {
    row0 = blockIdx.y * 128;
    n0 = blockIdx.x * 128;
  } else {
    int d = blockIdx.x;
    int xcd = d & 7;
    int n_t = (d >> 3) & ((1 << NTL) - 1);
    int rg  = d >> (3 + NTL);
    row0 = (rg * 8 + xcd) * 128;
    n0 = n_t * 128;
  }
  if (row0 >= padded_off[8]) return;
  int e = 0;
  while (row0 >= padded_off[e + 1]) ++e;
  int tid = threadIdx.x, lane = tid & 63, wv = tid >> 6;
  int wm = wv >> 1, wn = wv & 1;
  int fr = lane & 15, fq = lane >> 4;
  int ra0 = tid >> 2, ra1 = 64 + (tid >> 2);
  // pre-swizzled source chunk: physical chunk (tid&3) holds logical chunk
  // (tid&3)^((row>>1)&3); (row>>1)&3 == (tid>>3)&3 for both ra0 and ra1
  int ca = (((tid & 3) ^ ((tid >> 3) & 3))) * 8;
  const u16 *asrc0, *asrc1;
  if (MODE == 0) {
    asrc0 = Asrc + (size_t)row2tok[row0 + ra0] * KDIM + ca;
    asrc1 = Asrc + (size_t)row2tok[row0 + ra1] * KDIM + ca;
  } else {
    asrc0 = Asrc + (size_t)(row0 + ra0) * KDIM + ca;
    asrc1 = Asrc + (size_t)(row0 + ra1) * KDIM + ca;
  }
  const u16* bb = Wt + (size_t)e * (HID * DIM);
  const u16* bsrc0 = bb + (size_t)(n0 + ra0) * KDIM + ca;
  const u16* bsrc1 = bb + (size_t)(n0 + ra1) * KDIM + ca;
  int lo = wv * 512;   // wave-uniform LDS elem offset (64 lanes * 8 u16)
  // swizzled read: chunk fq of row (..+fr) is at physical fq^((fr>>1)&3)
  int sq = (fq ^ ((fr >> 1) & 3)) * 8;

  f32x4 acc[4][4];
#pragma unroll
  for (int i = 0; i < 4; ++i)
#pragma unroll
    for (int j = 0; j < 4; ++j) acc[i][j] = (f32x4){0.f, 0.f, 0.f, 0.f};
  bf16x8 av[4], bv[4];

#define STG(b, kt)                                 \
  do {                                             \
    int ko = (kt) * 32;                            \
    gload16(asrc0 + ko, &Abuf[b][lo]);             \
    gload16(asrc1 + ko, &Abuf[b][2048 + lo]);      \
    gload16(bsrc0 + ko, &Bbuf[b][lo]);             \
    gload16(bsrc1 + ko, &Bbuf[b][2048 + lo]);      \
  } while (0)

#define CMP(b)                                                                 \
  do {                                                                         \
    _Pragma("unroll") for (int fm = 0; fm < 4; ++fm)                           \
        av[fm] = *(const bf16x8*)&Abuf[b][(wm * 64 + fm * 16 + fr) * 32 + sq]; \
    _Pragma("unroll") for (int fn = 0; fn < 4; ++fn)                           \
        bv[fn] = *(const bf16x8*)&Bbuf[b][(wn * 64 + fn * 16 + fr) * 32 + sq]; \
    _Pragma("unroll") for (int fm = 0; fm < 4; ++fm)                           \
        _Pragma("unroll") for (int fn = 0; fn < 4; ++fn)                       \
            acc[fm][fn] = __builtin_amdgcn_mfma_f32_16x16x32_bf16(             \
                av[fm], bv[fn], acc[fm][fn], 0, 0, 0);                         \
  } while (0)

  constexpr int NK = KDIM / 32;
  STG(0, 0);
  STG(1, 1);
  int rb = 0;
  for (int kt = 0; kt < NK - 2; ++kt) {
    int sb = rb + 2; if (sb >= 3) sb -= 3;
    STG(sb, kt + 2);
    asm volatile("s_waitcnt vmcnt(8)" ::: "memory");
    asm volatile("s_barrier" ::: "memory");
    CMP(rb);
    asm volatile("s_waitcnt lgkmcnt(0)" ::: "memory");
    asm volatile("s_barrier" ::: "memory");
    if (++rb == 3) rb = 0;
  }
  asm volatile("s_waitcnt vmcnt(4)" ::: "memory");
  asm volatile("s_barrier" ::: "memory");
  CMP(rb);
  if (++rb == 3) rb = 0;
  asm volatile("s_waitcnt vmcnt(0)" ::: "memory");
  asm volatile("s_barrier" ::: "memory");
  CMP(rb);
#undef STG
#undef CMP

  float bv4[4];
#pragma unroll
  for (int fn = 0; fn < 4; ++fn)
    bv4[fn] = bias[e * NDIM + n0 + wn * 64 + fn * 16 + fr];

#pragma unroll
  for (int fm = 0; fm < 4; ++fm) {
#pragma unroll
    for (int j = 0; j < 4; ++j) {
      int grow = row0 + wm * 64 + fm * 16 + fq * 4 + j;
      u16* orow = Out + (size_t)grow * NDIM + n0 + wn * 64 + fr;
#pragma unroll
      for (int fn = 0; fn < 4; ++fn) {
        float v = acc[fm][fn][j] + bv4[fn];
        if (MODE == 0) v = v > 0.f ? v : 0.f;
        orow[fn * 16] = f2bf(v);
      }
    }
  }
}

// ---------------- final combine: out[n] = g0*y[s0] + g1*y[s1] ----------------

__global__ __launch_bounds__(256) void k_combine(
    const u16* __restrict__ y, const int* __restrict__ slots,
    const float* __restrict__ tok_g, float* __restrict__ out) {
  int n = blockIdx.x;
  int s0 = slots[2 * n], s1 = slots[2 * n + 1];
  float g0 = tok_g[2 * n], g1 = tok_g[2 * n + 1];
  int d = threadIdx.x * 4;
  ushort4 a = *(const ushort4*)(y + (size_t)s0 * DIM + d);
  ushort4 b = *(const ushort4*)(y + (size_t)s1 * DIM + d);
  float4 o;
  o.x = g0 * bf2f(a.x) + g1 * bf2f(b.x);
  o.y = g0 * bf2f(a.y) + g1 * bf2f(b.y);
  o.z = g0 * bf2f(a.z) + g1 * bf2f(b.z);
  o.w = g0 * bf2f(a.w) + g1 * bf2f(b.w);
  *(float4*)(out + (size_t)n * DIM + d) = o;
}

// ---------------- launch ----------------

extern "C" void kernel_launch(void* const* d_in, const int* in_sizes, int n_in,
                              void* d_out, int out_size, void* d_ws,
                              size_t ws_size, hipStream_t stream) {
  const float* x  = (const float*)d_in[0];
  const float* Wg = (const float*)d_in[1];
  const float* bg = (const float*)d_in[2];
  const float* W1 = (const float*)d_in[3];
  const float* b1 = (const float*)d_in[4];
  const float* W2 = (const float*)d_in[5];
  const float* b2 = (const float*)d_in[6];
  float* out = (float*)d_out;

  // workspace layout (bytes); total ~425 MiB.
  // y (PADROWS*DIM bf16 = 69.2 MB) reuses [0, 100663296) — xb and w1t are
  // both dead once gemm1 completes, and gemm2/combine run strictly after.
  char* w = (char*)d_ws;
  u16* xb          = (u16*)(w);                  // 33,554,432
  u16* y           = (u16*)(w);                  // 69,206,016 (after gemm1)
  u16* w1t         = (u16*)(w + 33554432);       // 67,108,864  [E][H][D]
  u16* w2t         = (u16*)(w + 100663296);      // 67,108,864  [E][D][H]
  u16* h           = (u16*)(w + 167772160);      // 276,824,064 [PADROWS][H]
  int* tok_e       = (int*)(w + 444596224);      // 131,072 (experts, then slots)
  float* tok_g     = (float*)(w + 444727296);    // 131,072
  int* counts      = (int*)(w + 444858368);
  int* cursor      = (int*)(w + 444858624);
  int* padded_off  = (int*)(w + 444858880);
  int* row2tok     = (int*)(w + 444859136);      // 135,168
  float* blocksums = (float*)(w + 445129472);    // 16,384

  k_zero<<<1, 64, 0, stream>>>(counts);
  k_gate<<<4096, 256, 0, stream>>>(x, Wg, bg, xb, tok_e, tok_g, blocksums);
  k_hist<<<16, 256, 0, stream>>>(tok_e, counts);
  k_setup<<<1, 256, 0, stream>>>(counts, blocksums, padded_off, cursor, row2tok,
                                 out + (size_t)N_TOK * DIM);
  k_scatter<<<64, 256, 0, stream>>>(tok_e, padded_off, cursor, row2tok);
  k_tcast<<<32768, 256, 0, stream>>>(W1, w1t, DIM, HID);
  k_tcast<<<32768, 256, 0, stream>>>(W2, w2t, HID, DIM);
  // gemm1: 2-D n-fastest grid (B-panel L2 reuse: XCD = n_t%8)
  k_gemm<DIM, 0, 0, 1><<<dim3(HID / 128, MTILES), 256, 0, stream>>>(
      xb, w1t, b1, row2tok, padded_off, h);
  // gemm2: 1-D XCD-grouped (A-panel L2 reuse: all n-siblings on one XCD)
  k_gemm<HID, 1, 3, 0><<<MTILES * (DIM / 128), 256, 0, stream>>>(
      h, w2t, b2, row2tok, padded_off, y);
  k_combine<<<N_TOK, 256, 0, stream>>>(y, tok_e, tok_g, out);
}